// Round 4
// baseline (80.656 us; speedup 1.0000x reference)
//
#include <hip/hip_runtime.h>
#include <hip/hip_bf16.h>
#include <hip/hip_cooperative_groups.h>

namespace cg = cooperative_groups;

#define NCLS 64
#define NSUP 5
#define NQRY 15
#define DIM  4096
#define NQTOT (NCLS * NQRY)   // 960
#define NQT   (NQTOT / 16)    // 60 query tiles
#define KC    4               // K-chunks per q-tile
#define NBLK  (NQT * KC)      // 240 blocks

typedef __attribute__((ext_vector_type(8))) short short8;
typedef __attribute__((ext_vector_type(4))) float f32x4;

__device__ __forceinline__ unsigned short f2bf(float f) {
    unsigned int u = __float_as_uint(f);
    u += 0x7FFFu + ((u >> 16) & 1u);   // RNE
    return (unsigned short)(u >> 16);
}
__device__ __forceinline__ float bf2f(unsigned short s) {
    return __uint_as_float(((unsigned int)s) << 16);
}

// Single cooperative kernel: phase1 prototypes -> grid.sync -> phase2 partial
// GEMM (qt x kc) -> grid.sync -> phase3 reduce + fused log_softmax/argmax.
__global__ __launch_bounds__(256) void proto_fused(
    const float* __restrict__ in, unsigned short* __restrict__ P,
    float* __restrict__ pnp, float* __restrict__ partials,
    float* __restrict__ out)
{
    __shared__ float s_part[4 * 16 * 66];   // phase2: [wave][row][col], pad 66
    __shared__ float s_red[8];              // phase1: [0..3]; phase3: l[0..3],a[4..7]

    cg::grid_group grid = cg::this_grid();
    const int b = blockIdx.x, tid = threadIdx.x;

    // ---------------- phase 1: prototypes (256 tasks over 240 blocks) -------
    for (int task = b; task < NCLS * 4; task += NBLK) {
        const int c = task >> 2, dc = task & 3;
        const int d = dc * 1024 + tid * 4;
        const float* base = in + (size_t)c * (NSUP + NQRY) * DIM + d;

        float4 s0 = *(const float4*)(base + 0 * DIM);
        float4 s1 = *(const float4*)(base + 1 * DIM);
        float4 s2 = *(const float4*)(base + 2 * DIM);
        float4 s3 = *(const float4*)(base + 3 * DIM);
        float4 s4 = *(const float4*)(base + 4 * DIM);
        float ax = 0.2f * (s0.x + s1.x + s2.x + s3.x + s4.x);
        float ay = 0.2f * (s0.y + s1.y + s2.y + s3.y + s4.y);
        float az = 0.2f * (s0.z + s1.z + s2.z + s3.z + s4.z);
        float aw = 0.2f * (s0.w + s1.w + s2.w + s3.w + s4.w);
        ushort4 o;
        o.x = f2bf(ax); o.y = f2bf(ay); o.z = f2bf(az); o.w = f2bf(aw);
        *(ushort4*)(P + (size_t)c * DIM + d) = o;

        // ||p||^2 from ROUNDED values (consistent with the 2*q.p MFMA term)
        float rx = bf2f(o.x), ry = bf2f(o.y), rz = bf2f(o.z), rw = bf2f(o.w);
        float pn = rx * rx + ry * ry + rz * rz + rw * rw;
        #pragma unroll
        for (int m = 32; m > 0; m >>= 1) pn += __shfl_xor(pn, m);
        if ((tid & 63) == 0) s_red[tid >> 6] = pn;
        __syncthreads();
        if (tid == 0) pnp[c * 4 + dc] = s_red[0] + s_red[1] + s_red[2] + s_red[3];
        __syncthreads();
    }
    if (b == 0 && tid == 0) { out[0] = 0.f; out[1] = 0.f; }

    grid.sync();

    // ---------------- phase 2: partial GEMM, block = (qt, kc) ---------------
    {
        const int w = tid >> 6, lane = tid & 63;
        const int m = lane & 15;       // A row (query) / B col (class)
        const int g = lane >> 4;       // k-group within MFMA step
        const int qt = b >> 2, kc = b & 3;
        const int qbase = qt * 16;
        const int kbase = kc * 1024 + w * 256;

        const int qi0 = qbase + m;
        const int rowA = (qi0 / NQRY) * (NSUP + NQRY) + NSUP + (qi0 % NQRY);
        const float* ap = in + (size_t)rowA * DIM + kbase + g * 8;
        const unsigned short* bp = P + (size_t)m * DIM + kbase + g * 8;

        f32x4 acc[4];
        #pragma unroll
        for (int i = 0; i < 4; ++i) acc[i] = (f32x4){0.f, 0.f, 0.f, 0.f};

        #pragma unroll
        for (int s = 0; s < 8; ++s) {
            const int ko = s * 32;
            float4 a0 = *(const float4*)(ap + ko);
            float4 a1 = *(const float4*)(ap + ko + 4);
            unsigned p0 = __builtin_amdgcn_perm(__float_as_uint(a0.y), __float_as_uint(a0.x), 0x07060302u);
            unsigned p1 = __builtin_amdgcn_perm(__float_as_uint(a0.w), __float_as_uint(a0.z), 0x07060302u);
            unsigned p2 = __builtin_amdgcn_perm(__float_as_uint(a1.y), __float_as_uint(a1.x), 0x07060302u);
            unsigned p3 = __builtin_amdgcn_perm(__float_as_uint(a1.w), __float_as_uint(a1.z), 0x07060302u);
            union { unsigned u[4]; short8 v; } au;
            au.u[0] = p0; au.u[1] = p1; au.u[2] = p2; au.u[3] = p3;
            short8 af = au.v;

            short8 b0 = *(const short8*)(bp + ko);
            short8 b1 = *(const short8*)(bp + ko + 16 * DIM);
            short8 b2 = *(const short8*)(bp + ko + 32 * DIM);
            short8 b3 = *(const short8*)(bp + ko + 48 * DIM);
            acc[0] = __builtin_amdgcn_mfma_f32_16x16x32_bf16(af, b0, acc[0], 0, 0, 0);
            acc[1] = __builtin_amdgcn_mfma_f32_16x16x32_bf16(af, b1, acc[1], 0, 0, 0);
            acc[2] = __builtin_amdgcn_mfma_f32_16x16x32_bf16(af, b2, acc[2], 0, 0, 0);
            acc[3] = __builtin_amdgcn_mfma_f32_16x16x32_bf16(af, b3, acc[3], 0, 0, 0);
        }

        // LDS partial store: C layout col=lane&15, row=(lane>>4)*4+j  [m89]
        #pragma unroll
        for (int cg2 = 0; cg2 < 4; ++cg2) {
            #pragma unroll
            for (int j = 0; j < 4; ++j)
                s_part[(w * 16 + g * 4 + j) * 66 + cg2 * 16 + m] = acc[cg2][j];
        }
        __syncthreads();

        // reduce 4 waves' partials -> global partial tile [16][64]
        const int col = tid & 63, r4 = tid >> 6;
        #pragma unroll
        for (int rr = 0; rr < 4; ++rr) {
            const int row = r4 * 4 + rr;
            float v = s_part[(0 * 16 + row) * 66 + col] + s_part[(1 * 16 + row) * 66 + col]
                    + s_part[(2 * 16 + row) * 66 + col] + s_part[(3 * 16 + row) * 66 + col];
            partials[(size_t)b * 1024 + row * 64 + col] = v;
        }
    }

    grid.sync();

    // ---------------- phase 3: blocks [0,60): reduce + softmax --------------
    if (b < NQT) {
        const int qt = b;
        const int qbase = qt * 16;
        const int col = tid & 63, wv = tid >> 6;
        float sl = 0.f, sa = 0.f;
        #pragma unroll
        for (int rr = 0; rr < 4; ++rr) {
            const int row = wv * 4 + rr;
            float v = 0.f;
            #pragma unroll
            for (int k2 = 0; k2 < KC; ++k2)
                v += partials[(size_t)(qt * KC + k2) * 1024 + row * 64 + col];
            float4 pp = *(const float4*)(pnp + col * 4);
            v = 2.f * v - (pp.x + pp.y + pp.z + pp.w);

            float mx = v; int am = col;
            #pragma unroll
            for (int msk = 1; msk < 64; msk <<= 1) {
                float vo = __shfl_xor(mx, msk);
                int   ao = __shfl_xor(am, msk);
                if (vo > mx || (vo == mx && ao < am)) { mx = vo; am = ao; }
            }
            float se = __expf(v - mx);
            #pragma unroll
            for (int msk = 1; msk < 64; msk <<= 1) se += __shfl_xor(se, msk);
            const float lse = mx + __logf(se);

            const int cc = (qbase + row) / NQRY;   // correct class (uniform/row)
            const float vc = __shfl(v, cc);
            if (col == 0) {
                sl += vc - lse;
                sa += (am == cc) ? 1.f : 0.f;
            }
        }
        if (col == 0) { s_red[wv] = sl; s_red[4 + wv] = sa; }
        __syncthreads();
        if (tid == 0) {
            float tl = s_red[0] + s_red[1] + s_red[2] + s_red[3];
            float ta = s_red[4] + s_red[5] + s_red[6] + s_red[7];
            atomicAdd(out + 0, tl * (-1.f / (float)NQTOT));
            atomicAdd(out + 1, ta * (1.f / (float)NQTOT));
        }
    }
}

extern "C" void kernel_launch(void* const* d_in, const int* in_sizes, int n_in,
                              void* d_out, int out_size, void* d_ws, size_t ws_size,
                              hipStream_t stream) {
    const float* in = (const float*)d_in[0];
    float* out = (float*)d_out;
    char* ws = (char*)d_ws;

    unsigned short* P = (unsigned short*)ws;        // 64*4096*2 = 524288 B
    float* pnp        = (float*)(ws + 524288);      // 1024 B
    float* partials   = (float*)(ws + 525568);      // 240*1024*4 = 983040 B

    void* args[] = { (void*)&in, (void*)&P, (void*)&pnp, (void*)&partials, (void*)&out };
    hipLaunchCooperativeKernel((void*)proto_fused, dim3(NBLK), dim3(256),
                               args, 0, stream);
}

// Round 5
// 39.021 us; speedup vs baseline: 2.0670x; 2.0670x over previous
//
#include <hip/hip_runtime.h>
#include <hip/hip_bf16.h>

#define NCLS 64
#define NSUP 5
#define NQRY 15
#define DIM  4096
#define NQTOT (NCLS * NQRY)   // 960
#define QB    4               // queries per block in K2
#define NBLK2 (NQTOT / QB)    // 240 blocks

typedef __attribute__((ext_vector_type(8))) short short8;
typedef __attribute__((ext_vector_type(4))) float f32x4;

__device__ __forceinline__ unsigned short f2bf(float f) {
    unsigned int u = __float_as_uint(f);
    u += 0x7FFFu + ((u >> 16) & 1u);   // RNE
    return (unsigned short)(u >> 16);
}
__device__ __forceinline__ float bf2f(unsigned short s) {
    return __uint_as_float(((unsigned int)s) << 16);
}

// K1: prototypes. 256 blocks: class c = b>>2, d-chunk dc = b&3 (1024 dims).
// Writes bf16 P[c][D], partial ||p||^2 -> pnp[c*4+dc]; block 0 zeroes out.
__global__ __launch_bounds__(256) void proto_prep(
    const float* __restrict__ in, unsigned short* __restrict__ P,
    float* __restrict__ pnp, float* __restrict__ out)
{
    const int b = blockIdx.x, t = threadIdx.x;
    const int c = b >> 2, dc = b & 3;
    const int d = dc * 1024 + t * 4;
    const float* base = in + (size_t)c * (NSUP + NQRY) * DIM + d;

    float4 s0 = *(const float4*)(base + 0 * DIM);
    float4 s1 = *(const float4*)(base + 1 * DIM);
    float4 s2 = *(const float4*)(base + 2 * DIM);
    float4 s3 = *(const float4*)(base + 3 * DIM);
    float4 s4 = *(const float4*)(base + 4 * DIM);
    float ax = 0.2f * (s0.x + s1.x + s2.x + s3.x + s4.x);
    float ay = 0.2f * (s0.y + s1.y + s2.y + s3.y + s4.y);
    float az = 0.2f * (s0.z + s1.z + s2.z + s3.z + s4.z);
    float aw = 0.2f * (s0.w + s1.w + s2.w + s3.w + s4.w);
    ushort4 o;
    o.x = f2bf(ax); o.y = f2bf(ay); o.z = f2bf(az); o.w = f2bf(aw);
    *(ushort4*)(P + (size_t)c * DIM + d) = o;

    // ||p||^2 from the ROUNDED values (consistent with the 2*q.p MFMA term)
    float rx = bf2f(o.x), ry = bf2f(o.y), rz = bf2f(o.z), rw = bf2f(o.w);
    float pn = rx * rx + ry * ry + rz * rz + rw * rw;

    #pragma unroll
    for (int m = 32; m > 0; m >>= 1) pn += __shfl_xor(pn, m);
    __shared__ float red[4];
    if ((t & 63) == 0) red[t >> 6] = pn;
    __syncthreads();
    if (t == 0) {
        pnp[c * 4 + dc] = red[0] + red[1] + red[2] + red[3];
        if (b == 0) { out[0] = 0.f; out[1] = 0.f; }
    }
}

// K2: 240 blocks x 256 threads (4 waves). Block = 4 queries x all 64 classes.
// Wave w owns K-chunk [w*1024, (w+1)*1024): 4 class-tiles (4 indep MFMA
// chains of 32). A-rows duplicate the 4 queries (row&3 = query), so every
// lane ends with acc[cg][j] = partial s(query j, class cg*16+lane&15).
// LDS reduce over waves, then wave r = query r's 64-lane softmax/argmax.
__global__ __launch_bounds__(256) void proto_score(
    const float* __restrict__ in, const unsigned short* __restrict__ P,
    const float* __restrict__ pnp, float* __restrict__ out)
{
    __shared__ float s_part[4 * 4 * 64];   // [wave][query][class]
    __shared__ float s_red[8];             // loss[0..3], acc[4..7]

    const int tid = threadIdx.x;
    const int w = tid >> 6, lane = tid & 63;
    const int m = lane & 15;       // A row / B row (class within tile)
    const int g = lane >> 4;       // k-group
    const int qbase = blockIdx.x * QB;
    const int kbase = w * 1024 + g * 8;

    // A: query (m&3), fp32 on-the-fly bf16 pack
    const int qi0 = qbase + (m & 3);
    const int rowA = (qi0 / NQRY) * (NSUP + NQRY) + NSUP + (qi0 % NQRY);
    const float* ap = in + (size_t)rowA * DIM + kbase;
    const unsigned short* bp = P + (size_t)m * DIM + kbase;

    f32x4 acc[4];
    #pragma unroll
    for (int i = 0; i < 4; ++i) acc[i] = (f32x4){0.f, 0.f, 0.f, 0.f};

    #pragma unroll 4
    for (int s = 0; s < 32; ++s) {
        const int ko = s * 32;
        float4 a0 = *(const float4*)(ap + ko);
        float4 a1 = *(const float4*)(ap + ko + 4);
        unsigned p0 = __builtin_amdgcn_perm(__float_as_uint(a0.y), __float_as_uint(a0.x), 0x07060302u);
        unsigned p1 = __builtin_amdgcn_perm(__float_as_uint(a0.w), __float_as_uint(a0.z), 0x07060302u);
        unsigned p2 = __builtin_amdgcn_perm(__float_as_uint(a1.y), __float_as_uint(a1.x), 0x07060302u);
        unsigned p3 = __builtin_amdgcn_perm(__float_as_uint(a1.w), __float_as_uint(a1.z), 0x07060302u);
        union { unsigned u[4]; short8 v; } au;
        au.u[0] = p0; au.u[1] = p1; au.u[2] = p2; au.u[3] = p3;
        short8 af = au.v;

        short8 b0 = *(const short8*)(bp + ko);
        short8 b1 = *(const short8*)(bp + ko + 16 * DIM);
        short8 b2 = *(const short8*)(bp + ko + 32 * DIM);
        short8 b3 = *(const short8*)(bp + ko + 48 * DIM);
        acc[0] = __builtin_amdgcn_mfma_f32_16x16x32_bf16(af, b0, acc[0], 0, 0, 0);
        acc[1] = __builtin_amdgcn_mfma_f32_16x16x32_bf16(af, b1, acc[1], 0, 0, 0);
        acc[2] = __builtin_amdgcn_mfma_f32_16x16x32_bf16(af, b2, acc[2], 0, 0, 0);
        acc[3] = __builtin_amdgcn_mfma_f32_16x16x32_bf16(af, b3, acc[3], 0, 0, 0);
    }

    // every lane holds all 4 queries for its class column; g==0 lanes write
    if (g == 0) {
        #pragma unroll
        for (int cg = 0; cg < 4; ++cg) {
            #pragma unroll
            for (int j = 0; j < 4; ++j)
                s_part[(w * 4 + j) * 64 + cg * 16 + m] = acc[cg][j];
        }
    }
    __syncthreads();

    // wave r handles query qbase+r; lane = class
    const int r = w;
    float v = s_part[(0 * 4 + r) * 64 + lane] + s_part[(1 * 4 + r) * 64 + lane]
            + s_part[(2 * 4 + r) * 64 + lane] + s_part[(3 * 4 + r) * 64 + lane];
    float4 pp = *(const float4*)(pnp + lane * 4);
    v = 2.f * v - (pp.x + pp.y + pp.z + pp.w);

    float mx = v; int am = lane;
    #pragma unroll
    for (int msk = 1; msk < 64; msk <<= 1) {
        float vo = __shfl_xor(mx, msk);
        int   ao = __shfl_xor(am, msk);
        if (vo > mx || (vo == mx && ao < am)) { mx = vo; am = ao; }
    }
    float se = __expf(v - mx);
    #pragma unroll
    for (int msk = 1; msk < 64; msk <<= 1) se += __shfl_xor(se, msk);
    const float lse = mx + __logf(se);

    const int cc = (qbase + r) / NQRY;     // correct class (uniform per wave)
    const float vc = __shfl(v, cc);
    if (lane == 0) {
        s_red[r]     = vc - lse;
        s_red[4 + r] = (am == cc) ? 1.f : 0.f;
    }
    __syncthreads();
    if (tid == 0) {
        float tl = s_red[0] + s_red[1] + s_red[2] + s_red[3];
        float ta = s_red[4] + s_red[5] + s_red[6] + s_red[7];
        atomicAdd(out + 0, tl * (-1.f / (float)NQTOT));
        atomicAdd(out + 1, ta * (1.f / (float)NQTOT));
    }
}

extern "C" void kernel_launch(void* const* d_in, const int* in_sizes, int n_in,
                              void* d_out, int out_size, void* d_ws, size_t ws_size,
                              hipStream_t stream) {
    const float* in = (const float*)d_in[0];
    float* out = (float*)d_out;
    char* ws = (char*)d_ws;

    unsigned short* P = (unsigned short*)ws;        // 64*4096*2 = 524288 B
    float* pnp        = (float*)(ws + 524288);      // 1024 B

    hipLaunchKernelGGL(proto_prep, dim3(256), dim3(256), 0, stream,
                       in, P, pnp, out);
    hipLaunchKernelGGL(proto_score, dim3(NBLK2), dim3(256), 0, stream,
                       in, P, pnp, out);
}

// Round 6
// 23.855 us; speedup vs baseline: 3.3811x; 1.6358x over previous
//
#include <hip/hip_runtime.h>
#include <hip/hip_bf16.h>

#define NCLS 64
#define NSUP 5
#define NQRY 15
#define DIM  4096
#define NQTOT (NCLS * NQRY)   // 960
#define NQT   (NQTOT / 16)    // 60 q-tiles (16 distinct queries each)
#define KC    8               // K-chunks per q-tile (chunk = 512 dims)
#define NBLK2 (NQT * KC)      // 480 blocks

typedef __attribute__((ext_vector_type(8))) short short8;
typedef __attribute__((ext_vector_type(4))) float f32x4;

__device__ __forceinline__ unsigned short f2bf(float f) {
    unsigned int u = __float_as_uint(f);
    u += 0x7FFFu + ((u >> 16) & 1u);   // RNE
    return (unsigned short)(u >> 16);
}
__device__ __forceinline__ float bf2f(unsigned short s) {
    return __uint_as_float(((unsigned int)s) << 16);
}

// K1: prototypes. 256 blocks: class c = b>>2, d-chunk dc = b&3 (1024 dims).
// Writes bf16 P[c][D], partial ||p||^2 -> pnp[c*4+dc]; block 0 zeroes out.
__global__ __launch_bounds__(256) void proto_prep(
    const float* __restrict__ in, unsigned short* __restrict__ P,
    float* __restrict__ pnp, float* __restrict__ out)
{
    const int b = blockIdx.x, t = threadIdx.x;
    const int c = b >> 2, dc = b & 3;
    const int d = dc * 1024 + t * 4;
    const float* base = in + (size_t)c * (NSUP + NQRY) * DIM + d;

    float4 s0 = *(const float4*)(base + 0 * DIM);
    float4 s1 = *(const float4*)(base + 1 * DIM);
    float4 s2 = *(const float4*)(base + 2 * DIM);
    float4 s3 = *(const float4*)(base + 3 * DIM);
    float4 s4 = *(const float4*)(base + 4 * DIM);
    float ax = 0.2f * (s0.x + s1.x + s2.x + s3.x + s4.x);
    float ay = 0.2f * (s0.y + s1.y + s2.y + s3.y + s4.y);
    float az = 0.2f * (s0.z + s1.z + s2.z + s3.z + s4.z);
    float aw = 0.2f * (s0.w + s1.w + s2.w + s3.w + s4.w);
    ushort4 o;
    o.x = f2bf(ax); o.y = f2bf(ay); o.z = f2bf(az); o.w = f2bf(aw);
    *(ushort4*)(P + (size_t)c * DIM + d) = o;

    // ||p||^2 from the ROUNDED values (consistent with the 2*q.p MFMA term)
    float rx = bf2f(o.x), ry = bf2f(o.y), rz = bf2f(o.z), rw = bf2f(o.w);
    float pn = rx * rx + ry * ry + rz * rz + rw * rw;

    #pragma unroll
    for (int m = 32; m > 0; m >>= 1) pn += __shfl_xor(pn, m);
    __shared__ float red[4];
    if ((t & 63) == 0) red[t >> 6] = pn;
    __syncthreads();
    if (t == 0) {
        pnp[c * 4 + dc] = red[0] + red[1] + red[2] + red[3];
        if (b == 0) { out[0] = 0.f; out[1] = 0.f; }
    }
}

// K2a: 480 blocks (60 q-tiles x 8 K-chunks) x 256 threads (4 waves).
// Block computes partial 16x64 score tile over its K=512 chunk.
// Wave w owns K=[kc*512 + w*128, +128): 4 MFMA steps x 4 class-tiles.
// 16 DISTINCT queries per block (A row m = query qbase+m, as validated in
// R1-R3, absmax 0.0). LDS reduce over waves, write partial tile to global.
__global__ __launch_bounds__(256) void proto_part(
    const float* __restrict__ in, const unsigned short* __restrict__ P,
    float* __restrict__ partials)
{
    __shared__ float part[4 * 16 * 66];   // [wave][row][col], pad 66

    const int tid = threadIdx.x;
    const int w = tid >> 6, lane = tid & 63;
    const int m = lane & 15;       // A row (query) / B col (class)
    const int g = lane >> 4;       // k-group within MFMA step
    const int qt = blockIdx.x / KC, kc = blockIdx.x % KC;
    const int qbase = qt * 16;
    const int kbase = kc * 512 + w * 128 + g * 8;

    const int qi0 = qbase + m;
    const int rowA = (qi0 / NQRY) * (NSUP + NQRY) + NSUP + (qi0 % NQRY);
    const float* ap = in + (size_t)rowA * DIM + kbase;
    const unsigned short* bp = P + (size_t)m * DIM + kbase;

    f32x4 acc[4];
    #pragma unroll
    for (int i = 0; i < 4; ++i) acc[i] = (f32x4){0.f, 0.f, 0.f, 0.f};

    #pragma unroll
    for (int s = 0; s < 4; ++s) {          // 4 K-steps of 32
        const int ko = s * 32;
        float4 a0 = *(const float4*)(ap + ko);
        float4 a1 = *(const float4*)(ap + ko + 4);
        unsigned p0 = __builtin_amdgcn_perm(__float_as_uint(a0.y), __float_as_uint(a0.x), 0x07060302u);
        unsigned p1 = __builtin_amdgcn_perm(__float_as_uint(a0.w), __float_as_uint(a0.z), 0x07060302u);
        unsigned p2 = __builtin_amdgcn_perm(__float_as_uint(a1.y), __float_as_uint(a1.x), 0x07060302u);
        unsigned p3 = __builtin_amdgcn_perm(__float_as_uint(a1.w), __float_as_uint(a1.z), 0x07060302u);
        union { unsigned u[4]; short8 v; } au;
        au.u[0] = p0; au.u[1] = p1; au.u[2] = p2; au.u[3] = p3;
        short8 af = au.v;

        short8 b0 = *(const short8*)(bp + ko);
        short8 b1 = *(const short8*)(bp + ko + 16 * DIM);
        short8 b2 = *(const short8*)(bp + ko + 32 * DIM);
        short8 b3 = *(const short8*)(bp + ko + 48 * DIM);
        acc[0] = __builtin_amdgcn_mfma_f32_16x16x32_bf16(af, b0, acc[0], 0, 0, 0);
        acc[1] = __builtin_amdgcn_mfma_f32_16x16x32_bf16(af, b1, acc[1], 0, 0, 0);
        acc[2] = __builtin_amdgcn_mfma_f32_16x16x32_bf16(af, b2, acc[2], 0, 0, 0);
        acc[3] = __builtin_amdgcn_mfma_f32_16x16x32_bf16(af, b3, acc[3], 0, 0, 0);
    }

    // LDS partial store: C layout col=lane&15, row=(lane>>4)*4+j  [m89]
    #pragma unroll
    for (int cg = 0; cg < 4; ++cg) {
        #pragma unroll
        for (int j = 0; j < 4; ++j)
            part[(w * 16 + g * 4 + j) * 66 + cg * 16 + m] = acc[cg][j];
    }
    __syncthreads();

    // reduce 4 waves' K-partials -> global partial tile [16][64]
    const int col = tid & 63, r4 = tid >> 6;
    #pragma unroll
    for (int rr = 0; rr < 4; ++rr) {
        const int row = r4 * 4 + rr;
        float v = part[(0 * 16 + row) * 66 + col] + part[(1 * 16 + row) * 66 + col]
                + part[(2 * 16 + row) * 66 + col] + part[(3 * 16 + row) * 66 + col];
        partials[(size_t)blockIdx.x * 1024 + row * 64 + col] = v;
    }
}

// K2b: 60 blocks x 256 threads. Reduce 8 K-chunk partials + fused
// log_softmax/argmax + loss/acc atomics (R2/R3-validated phase-3 code).
__global__ __launch_bounds__(256) void proto_final(
    const float* __restrict__ partials, const float* __restrict__ pnp,
    float* __restrict__ out)
{
    __shared__ float red_l[4], red_a[4];
    const int qt = blockIdx.x, tid = threadIdx.x;
    const int qbase = qt * 16;
    const int col = tid & 63, wv = tid >> 6;

    float sl = 0.f, sa = 0.f;
    #pragma unroll
    for (int rr = 0; rr < 4; ++rr) {
        const int row = wv * 4 + rr;
        float v = 0.f;
        #pragma unroll
        for (int k2 = 0; k2 < KC; ++k2)
            v += partials[(size_t)(qt * KC + k2) * 1024 + row * 64 + col];
        float4 pp = *(const float4*)(pnp + col * 4);
        v = 2.f * v - (pp.x + pp.y + pp.z + pp.w);

        float mx = v; int am = col;
        #pragma unroll
        for (int msk = 1; msk < 64; msk <<= 1) {
            float vo = __shfl_xor(mx, msk);
            int   ao = __shfl_xor(am, msk);
            if (vo > mx || (vo == mx && ao < am)) { mx = vo; am = ao; }
        }
        float se = __expf(v - mx);
        #pragma unroll
        for (int msk = 1; msk < 64; msk <<= 1) se += __shfl_xor(se, msk);
        const float lse = mx + __logf(se);

        const int cc = (qbase + row) / NQRY;   // correct class (uniform/row)
        const float vc = __shfl(v, cc);
        if (col == 0) {
            sl += vc - lse;
            sa += (am == cc) ? 1.f : 0.f;
        }
    }
    if (col == 0) { red_l[wv] = sl; red_a[wv] = sa; }
    __syncthreads();
    if (tid == 0) {
        float tl = red_l[0] + red_l[1] + red_l[2] + red_l[3];
        float ta = red_a[0] + red_a[1] + red_a[2] + red_a[3];
        atomicAdd(out + 0, tl * (-1.f / (float)NQTOT));
        atomicAdd(out + 1, ta * (1.f / (float)NQTOT));
    }
}

extern "C" void kernel_launch(void* const* d_in, const int* in_sizes, int n_in,
                              void* d_out, int out_size, void* d_ws, size_t ws_size,
                              hipStream_t stream) {
    const float* in = (const float*)d_in[0];
    float* out = (float*)d_out;
    char* ws = (char*)d_ws;

    unsigned short* P = (unsigned short*)ws;        // 64*4096*2 = 524288 B
    float* pnp        = (float*)(ws + 524288);      // 1024 B
    float* partials   = (float*)(ws + 525568);      // 480*1024*4 = 1966080 B

    hipLaunchKernelGGL(proto_prep, dim3(256), dim3(256), 0, stream,
                       in, P, pnp, out);
    hipLaunchKernelGGL(proto_part, dim3(NBLK2), dim3(256), 0, stream,
                       in, P, partials);
    hipLaunchKernelGGL(proto_final, dim3(NQT), dim3(256), 0, stream,
                       partials, pnp, out);
}

// Round 7
// 23.793 us; speedup vs baseline: 3.3899x; 1.0026x over previous
//
#include <hip/hip_runtime.h>
#include <hip/hip_bf16.h>

#define NCLS 64
#define NSUP 5
#define NQRY 15
#define DIM  4096
#define NQTOT (NCLS * NQRY)   // 960
#define NQT   (NQTOT / 16)    // 60 q-tiles (16 distinct queries each)
#define KC    8               // K-chunks per q-tile (chunk = 512 dims)
#define NBLK2 (NQT * KC)      // 480 blocks

typedef __attribute__((ext_vector_type(8))) short short8;
typedef __attribute__((ext_vector_type(4))) float f32x4;

__device__ __forceinline__ unsigned short f2bf(float f) {
    unsigned int u = __float_as_uint(f);
    u += 0x7FFFu + ((u >> 16) & 1u);   // RNE
    return (unsigned short)(u >> 16);
}
__device__ __forceinline__ float bf2f(unsigned short s) {
    return __uint_as_float(((unsigned int)s) << 16);
}

// K1: prototypes. 256 blocks: class c = b>>2, d-chunk dc = b&3 (1024 dims).
// Writes bf16 P[c][D], partial ||p||^2 -> pnp[c*4+dc]; block 0 zeroes out.
__global__ __launch_bounds__(256) void proto_prep(
    const float* __restrict__ in, unsigned short* __restrict__ P,
    float* __restrict__ pnp, float* __restrict__ out)
{
    const int b = blockIdx.x, t = threadIdx.x;
    const int c = b >> 2, dc = b & 3;
    const int d = dc * 1024 + t * 4;
    const float* base = in + (size_t)c * (NSUP + NQRY) * DIM + d;

    float4 s0 = *(const float4*)(base + 0 * DIM);
    float4 s1 = *(const float4*)(base + 1 * DIM);
    float4 s2 = *(const float4*)(base + 2 * DIM);
    float4 s3 = *(const float4*)(base + 3 * DIM);
    float4 s4 = *(const float4*)(base + 4 * DIM);
    float ax = 0.2f * (s0.x + s1.x + s2.x + s3.x + s4.x);
    float ay = 0.2f * (s0.y + s1.y + s2.y + s3.y + s4.y);
    float az = 0.2f * (s0.z + s1.z + s2.z + s3.z + s4.z);
    float aw = 0.2f * (s0.w + s1.w + s2.w + s3.w + s4.w);
    ushort4 o;
    o.x = f2bf(ax); o.y = f2bf(ay); o.z = f2bf(az); o.w = f2bf(aw);
    *(ushort4*)(P + (size_t)c * DIM + d) = o;

    // ||p||^2 from the ROUNDED values (consistent with the 2*q.p MFMA term)
    float rx = bf2f(o.x), ry = bf2f(o.y), rz = bf2f(o.z), rw = bf2f(o.w);
    float pn = rx * rx + ry * ry + rz * rz + rw * rw;

    #pragma unroll
    for (int m = 32; m > 0; m >>= 1) pn += __shfl_xor(pn, m);
    __shared__ float red[4];
    if ((t & 63) == 0) red[t >> 6] = pn;
    __syncthreads();
    if (t == 0) {
        pnp[c * 4 + dc] = red[0] + red[1] + red[2] + red[3];
        if (b == 0) { out[0] = 0.f; out[1] = 0.f; }
    }
}

// K2a: 480 blocks (60 q-tiles x 8 K-chunks) x 512 threads (8 waves).
// Block computes partial 16x64 score tile over its K=512 chunk.
// Wave w owns K=[kc*512 + w*64, +64): 2 MFMA steps x 4 class-tiles.
// 16 DISTINCT queries per block (A row m = query qbase+m; R1-R3/R5
// validated, absmax 0.0). LDS reduce over 8 waves -> global partial tile.
__global__ __launch_bounds__(512) void proto_part(
    const float* __restrict__ in, const unsigned short* __restrict__ P,
    float* __restrict__ partials)
{
    __shared__ float part[8 * 16 * 66];   // [wave][row][col], pad 66

    const int tid = threadIdx.x;
    const int w = tid >> 6, lane = tid & 63;
    const int m = lane & 15;       // A row (query) / B col (class)
    const int g = lane >> 4;       // k-group within MFMA step
    const int qt = blockIdx.x / KC, kc = blockIdx.x % KC;
    const int qbase = qt * 16;
    const int kbase = kc * 512 + w * 64 + g * 8;

    const int qi0 = qbase + m;
    const int rowA = (qi0 / NQRY) * (NSUP + NQRY) + NSUP + (qi0 % NQRY);
    const float* ap = in + (size_t)rowA * DIM + kbase;
    const unsigned short* bp = P + (size_t)m * DIM + kbase;

    f32x4 acc[4];
    #pragma unroll
    for (int i = 0; i < 4; ++i) acc[i] = (f32x4){0.f, 0.f, 0.f, 0.f};

    #pragma unroll
    for (int s = 0; s < 2; ++s) {          // 2 K-steps of 32
        const int ko = s * 32;
        float4 a0 = *(const float4*)(ap + ko);
        float4 a1 = *(const float4*)(ap + ko + 4);
        unsigned p0 = __builtin_amdgcn_perm(__float_as_uint(a0.y), __float_as_uint(a0.x), 0x07060302u);
        unsigned p1 = __builtin_amdgcn_perm(__float_as_uint(a0.w), __float_as_uint(a0.z), 0x07060302u);
        unsigned p2 = __builtin_amdgcn_perm(__float_as_uint(a1.y), __float_as_uint(a1.x), 0x07060302u);
        unsigned p3 = __builtin_amdgcn_perm(__float_as_uint(a1.w), __float_as_uint(a1.z), 0x07060302u);
        union { unsigned u[4]; short8 v; } au;
        au.u[0] = p0; au.u[1] = p1; au.u[2] = p2; au.u[3] = p3;
        short8 af = au.v;

        short8 b0 = *(const short8*)(bp + ko);
        short8 b1 = *(const short8*)(bp + ko + 16 * DIM);
        short8 b2 = *(const short8*)(bp + ko + 32 * DIM);
        short8 b3 = *(const short8*)(bp + ko + 48 * DIM);
        acc[0] = __builtin_amdgcn_mfma_f32_16x16x32_bf16(af, b0, acc[0], 0, 0, 0);
        acc[1] = __builtin_amdgcn_mfma_f32_16x16x32_bf16(af, b1, acc[1], 0, 0, 0);
        acc[2] = __builtin_amdgcn_mfma_f32_16x16x32_bf16(af, b2, acc[2], 0, 0, 0);
        acc[3] = __builtin_amdgcn_mfma_f32_16x16x32_bf16(af, b3, acc[3], 0, 0, 0);
    }

    // LDS partial store: C layout col=lane&15, row=(lane>>4)*4+j  [m89]
    #pragma unroll
    for (int cg = 0; cg < 4; ++cg) {
        #pragma unroll
        for (int j = 0; j < 4; ++j)
            part[(w * 16 + g * 4 + j) * 66 + cg * 16 + m] = acc[cg][j];
    }
    __syncthreads();

    // reduce 8 waves' K-partials -> global partial tile [16][64]
    const int col = tid & 63, r8 = tid >> 6;
    #pragma unroll
    for (int rr = 0; rr < 2; ++rr) {
        const int row = r8 * 2 + rr;
        float v = 0.f;
        #pragma unroll
        for (int wv = 0; wv < 8; ++wv)
            v += part[(wv * 16 + row) * 66 + col];
        partials[(size_t)blockIdx.x * 1024 + row * 64 + col] = v;
    }
}

// K2b: 60 blocks x 256 threads. Reduce 8 K-chunk partials + fused
// log_softmax/argmax + loss/acc atomics (R2/R3/R5-validated code).
__global__ __launch_bounds__(256) void proto_final(
    const float* __restrict__ partials, const float* __restrict__ pnp,
    float* __restrict__ out)
{
    __shared__ float red_l[4], red_a[4];
    const int qt = blockIdx.x, tid = threadIdx.x;
    const int qbase = qt * 16;
    const int col = tid & 63, wv = tid >> 6;

    float sl = 0.f, sa = 0.f;
    #pragma unroll
    for (int rr = 0; rr < 4; ++rr) {
        const int row = wv * 4 + rr;
        float v = 0.f;
        #pragma unroll
        for (int k2 = 0; k2 < KC; ++k2)
            v += partials[(size_t)(qt * KC + k2) * 1024 + row * 64 + col];
        float4 pp = *(const float4*)(pnp + col * 4);
        v = 2.f * v - (pp.x + pp.y + pp.z + pp.w);

        float mx = v; int am = col;
        #pragma unroll
        for (int msk = 1; msk < 64; msk <<= 1) {
            float vo = __shfl_xor(mx, msk);
            int   ao = __shfl_xor(am, msk);
            if (vo > mx || (vo == mx && ao < am)) { mx = vo; am = ao; }
        }
        float se = __expf(v - mx);
        #pragma unroll
        for (int msk = 1; msk < 64; msk <<= 1) se += __shfl_xor(se, msk);
        const float lse = mx + __logf(se);

        const int cc = (qbase + row) / NQRY;   // correct class (uniform/row)
        const float vc = __shfl(v, cc);
        if (col == 0) {
            sl += vc - lse;
            sa += (am == cc) ? 1.f : 0.f;
        }
    }
    if (col == 0) { red_l[wv] = sl; red_a[wv] = sa; }
    __syncthreads();
    if (tid == 0) {
        float tl = red_l[0] + red_l[1] + red_l[2] + red_l[3];
        float ta = red_a[0] + red_a[1] + red_a[2] + red_a[3];
        atomicAdd(out + 0, tl * (-1.f / (float)NQTOT));
        atomicAdd(out + 1, ta * (1.f / (float)NQTOT));
    }
}

extern "C" void kernel_launch(void* const* d_in, const int* in_sizes, int n_in,
                              void* d_out, int out_size, void* d_ws, size_t ws_size,
                              hipStream_t stream) {
    const float* in = (const float*)d_in[0];
    float* out = (float*)d_out;
    char* ws = (char*)d_ws;

    unsigned short* P = (unsigned short*)ws;        // 64*4096*2 = 524288 B
    float* pnp        = (float*)(ws + 524288);      // 1024 B
    float* partials   = (float*)(ws + 525568);      // 480*1024*4 = 1966080 B

    hipLaunchKernelGGL(proto_prep, dim3(256), dim3(256), 0, stream,
                       in, P, pnp, out);
    hipLaunchKernelGGL(proto_part, dim3(NBLK2), dim3(512), 0, stream,
                       in, P, partials);
    hipLaunchKernelGGL(proto_final, dim3(NQT), dim3(256), 0, stream,
                       partials, pnp, out);
}